// Round 4
// baseline (793.603 us; speedup 1.0000x reference)
//
#include <hip/hip_runtime.h>
#include <cstdint>

#define NN 10000
#define NE 80000
#define DIN_ 1024
#define HH 512

typedef __attribute__((ext_vector_type(8))) short bf16x8;
typedef __attribute__((ext_vector_type(4))) float f32x4;
typedef unsigned short u16;
typedef unsigned int u32;

static __device__ __forceinline__ float b2f(u16 u) {
  u32 i = ((u32)u) << 16;
  return __builtin_bit_cast(float, i);
}
static __device__ __forceinline__ u16 f2b(float f) {
  u32 i = __builtin_bit_cast(u32, f);
  u32 r = (i + 0x7fffu + ((i >> 16) & 1u)) >> 16;
  return (u16)r;
}
static __device__ __forceinline__ void load8(const u16* p, float* f) {
  uint4 u = *(const uint4*)p;
  f[0] = __builtin_bit_cast(float, u.x << 16);
  f[1] = __builtin_bit_cast(float, u.x & 0xffff0000u);
  f[2] = __builtin_bit_cast(float, u.y << 16);
  f[3] = __builtin_bit_cast(float, u.y & 0xffff0000u);
  f[4] = __builtin_bit_cast(float, u.z << 16);
  f[5] = __builtin_bit_cast(float, u.z & 0xffff0000u);
  f[6] = __builtin_bit_cast(float, u.w << 16);
  f[7] = __builtin_bit_cast(float, u.w & 0xffff0000u);
}

// ---------------- dtype probe ----------------
// flags[0]=1 if float tensors are fp32 (else bf16); flags[1]=1 if edge_index is int64 (else int32)
__global__ void k_probe(const u16* xw, const u32* ew, int* flags) {
  __shared__ int c0, c1;
  if (threadIdx.x == 0) { c0 = 0; c1 = 0; }
  __syncthreads();
  int t = threadIdx.x;
  int bad = 0;
  for (int i = t; i < 2048; i += 256) {
    u32 e = (xw[i] >> 7) & 0xFFu;  // bf16 exponent field
    if (e >= 140u) bad++;          // |v| >= 2^13: impossible for bf16 x~N(0,1)
  }
  if (bad) atomicAdd(&c0, bad);
  int z = 0;
  for (int i = t; i < 512; i += 256)
    if (ew[2 * i + 1] == 0u) z++;  // int64 high words are all zero
  if (z) atomicAdd(&c1, z);
  __syncthreads();
  if (t == 0) {
    flags[0] = (c0 > 64) ? 1 : 0;
    flags[1] = (c1 > 200) ? 1 : 0;
  }
}

// ---------------- canonicalization ----------------
__global__ void k_cvt_edges(const void* ei, int* s, int* d, const int* flags) {
  int i = blockIdx.x * blockDim.x + threadIdx.x;
  if (i >= NE) return;
  if (flags[1]) {
    const long long* p = (const long long*)ei;
    s[i] = (int)p[i];
    d[i] = (int)p[NE + i];
  } else {
    const int* p = (const int*)ei;
    s[i] = p[i];
    d[i] = p[NE + i];
  }
}

__global__ void k_cvt_x(const void* in, u16* out, int n, const int* flags) {
  int f = flags[0];
  for (int i = blockIdx.x * blockDim.x + threadIdx.x; i < n; i += gridDim.x * blockDim.x)
    out[i] = f ? f2b(((const float*)in)[i]) : ((const u16*)in)[i];
}

struct VecCvt {
  const void* in[20];
  u16* out[20];
  int n[20];
};
__global__ void k_cvt_vecs(VecCvt a, const int* flags) {
  int tsel = blockIdx.x;
  int f = flags[0];
  int n = a.n[tsel];
  const void* in = a.in[tsel];
  u16* out = a.out[tsel];
  for (int i = threadIdx.x; i < n; i += 256)
    out[i] = f ? f2b(((const float*)in)[i]) : ((const u16*)in)[i];
}

// fused dtype-convert + transpose: in [K,N] (fp32 or bf16) -> out bf16 [N,K]
__global__ void k_trc(const void* in, u16* out, int K, int N, const int* flags) {
  __shared__ u16 t[32][33];
  int f = flags[0];
  int n0 = blockIdx.x * 32, k0 = blockIdx.y * 32;
  int tx = threadIdx.x, ty = threadIdx.y;
  for (int r = ty; r < 32; r += 8) {
    size_t idx = (size_t)(k0 + r) * N + n0 + tx;
    t[r][tx] = f ? f2b(((const float*)in)[idx]) : ((const u16*)in)[idx];
  }
  __syncthreads();
  for (int r = ty; r < 32; r += 8) out[(size_t)(n0 + r) * K + k0 + tx] = t[tx][r];
}

// ---------------- CSR build ----------------
__global__ void k_count(const int* dst, int* counts, int E, int n) {
  int i = blockIdx.x * blockDim.x + threadIdx.x;
  if (i < E) atomicAdd(&counts[dst[i]], 1);
  else if (i < E + n) atomicAdd(&counts[i - E], 1);  // self-loop
}

__global__ void k_scan(const int* counts, int* rowptr, int n) {
  __shared__ int lds[1024];
  __shared__ int carry;
  int t = threadIdx.x;
  if (t == 0) { carry = 0; rowptr[0] = 0; }
  __syncthreads();
  for (int base = 0; base < n; base += 1024) {
    int v = (base + t < n) ? counts[base + t] : 0;
    lds[t] = v;
    __syncthreads();
    for (int off = 1; off < 1024; off <<= 1) {
      int x = (t >= off) ? lds[t - off] : 0;
      __syncthreads();
      lds[t] += x;
      __syncthreads();
    }
    if (base + t < n) rowptr[base + t + 1] = lds[t] + carry;
    __syncthreads();
    if (t == 1023) carry += lds[1023];
    __syncthreads();
  }
}

__global__ void k_copy(const int* a, int* b, int n) {
  int i = blockIdx.x * blockDim.x + threadIdx.x;
  if (i < n) b[i] = a[i];
}

__global__ void k_scatter(const int* src, const int* dst, int* cursor, int* col, int E, int n) {
  int i = blockIdx.x * blockDim.x + threadIdx.x;
  if (i < E) {
    int p = atomicAdd(&cursor[dst[i]], 1);
    col[p] = src[i];
  } else if (i < E + n) {
    int v = i - E;
    int p = atomicAdd(&cursor[v], 1);
    col[p] = v;  // self-loop
  }
}

// ---------------- MFMA GEMM: C[M,N] = A[M,K] @ Bt[N,K]^T + bias, opt relu ----------------
__global__ __launch_bounds__(256) void k_gemm(const u16* __restrict__ A, const u16* __restrict__ Bt,
                                              const u16* __restrict__ bias, u16* __restrict__ C,
                                              int M, int N, int K, int act, int total_waves) {
  int wid = (blockIdx.x * 256 + threadIdx.x) >> 6;
  if (wid >= total_waves) return;
  int lane = threadIdx.x & 63;
  int tiles_n = N >> 6;
  int tm = wid / tiles_n, tn = wid - tm * tiles_n;
  int m0 = tm << 6, n0 = tn << 6;
  int lr = lane & 15, lk = (lane >> 4) << 3;

  const u16* ap[4];
  const u16* bp[4];
#pragma unroll
  for (int i = 0; i < 4; i++) {
    int r = m0 + i * 16 + lr;
    r = r < M ? r : M - 1;
    ap[i] = A + (size_t)r * K + lk;
    bp[i] = Bt + (size_t)(n0 + i * 16 + lr) * K + lk;
  }
  f32x4 acc[4][4];
#pragma unroll
  for (int i = 0; i < 4; i++)
#pragma unroll
    for (int j = 0; j < 4; j++) acc[i][j] = (f32x4){0.f, 0.f, 0.f, 0.f};

  for (int k = 0; k < K; k += 32) {
    bf16x8 a[4], b[4];
#pragma unroll
    for (int i = 0; i < 4; i++) a[i] = *(const bf16x8*)(ap[i] + k);
#pragma unroll
    for (int i = 0; i < 4; i++) b[i] = *(const bf16x8*)(bp[i] + k);
#pragma unroll
    for (int i = 0; i < 4; i++)
#pragma unroll
      for (int j = 0; j < 4; j++)
        acc[i][j] = __builtin_amdgcn_mfma_f32_16x16x32_bf16(a[i], b[j], acc[i][j], 0, 0, 0);
  }

  int rbase = (lane >> 4) << 2;
#pragma unroll
  for (int i = 0; i < 4; i++) {
#pragma unroll
    for (int j = 0; j < 4; j++) {
      int colc = n0 + j * 16 + lr;
      float bv = b2f(bias[colc]);
#pragma unroll
      for (int r = 0; r < 4; r++) {
        int row = m0 + i * 16 + rbase + r;
        if (row < M) {
          float v = acc[i][j][r] + bv;
          if (act) v = fmaxf(v, 0.f);
          C[(size_t)row * N + colc] = f2b(v);
        }
      }
    }
  }
}

// ---------------- GATv2 attention + aggregation, one wave per dst node ----------------
// NOTE: out may alias xr (wave only reads xr[node] before writing out[node])
__global__ __launch_bounds__(256) void k_attn(const u16* __restrict__ xl, const u16* __restrict__ xr,
                                              const u16* __restrict__ att, const u16* __restrict__ bias,
                                              const int* __restrict__ rowptr, const int* __restrict__ col,
                                              u16* __restrict__ out, int n) {
  int node = (blockIdx.x * 256 + threadIdx.x) >> 6;
  if (node >= n) return;
  int lane = threadIdx.x & 63;
  int h0 = lane * 8;
  float a[8], r[8];
  load8(att + h0, a);
  load8(xr + (size_t)node * HH + h0, r);
  int e0 = rowptr[node], e1 = rowptr[node + 1];

  float m = -3e38f, s = 0.f;
  for (int e = e0; e < e1; e++) {
    int j = col[e];
    float xv[8];
    load8(xl + (size_t)j * HH + h0, xv);
    float part = 0.f;
#pragma unroll
    for (int i = 0; i < 8; i++) {
      float z = xv[i] + r[i];
      z = z > 0.f ? z : 0.2f * z;
      part = fmaf(a[i], z, part);
    }
#pragma unroll
    for (int off = 32; off >= 1; off >>= 1) part += __shfl_xor(part, off);
    float mn = fmaxf(m, part);
    s = s * __expf(m - mn) + __expf(part - mn);
    m = mn;
  }
  float inv = 1.f / (s + 1e-16f);

  float acc[8] = {0.f, 0.f, 0.f, 0.f, 0.f, 0.f, 0.f, 0.f};
  for (int e = e0; e < e1; e++) {
    int j = col[e];
    float xv[8];
    load8(xl + (size_t)j * HH + h0, xv);
    float part = 0.f;
#pragma unroll
    for (int i = 0; i < 8; i++) {
      float z = xv[i] + r[i];
      z = z > 0.f ? z : 0.2f * z;
      part = fmaf(a[i], z, part);
    }
#pragma unroll
    for (int off = 32; off >= 1; off >>= 1) part += __shfl_xor(part, off);
    float w = __expf(part - m) * inv;
#pragma unroll
    for (int i = 0; i < 8; i++) acc[i] = fmaf(w, xv[i], acc[i]);
  }

  float bv[8];
  load8(bias + h0, bv);
  uint4 o;
  u32 p[8];
#pragma unroll
  for (int i = 0; i < 8; i++) {
    float v = acc[i] + bv[i];
    v = fmaxf(v, 0.f);
    p[i] = f2b(v);
  }
  o.x = p[0] | (p[1] << 16);
  o.y = p[2] | (p[3] << 16);
  o.z = p[4] | (p[5] << 16);
  o.w = p[6] | (p[7] << 16);
  *(uint4*)(out + (size_t)node * HH + h0) = o;
}

// ---------------- final linear (256->2) + softmax; OUTPUT IS FLOAT32 ----------------
__global__ __launch_bounds__(256) void k_head(const u16* __restrict__ h2, const u16* __restrict__ lw3,
                                              const u16* __restrict__ lb3, float* __restrict__ out, int n) {
  int row = (blockIdx.x * 256 + threadIdx.x) >> 6;
  if (row >= n) return;
  int lane = threadIdx.x & 63;
  int k0 = lane * 4;
  const u16* hp = h2 + (size_t)row * 256 + k0;
  uint2 hu = *(const uint2*)hp;
  float hx[4];
  hx[0] = __builtin_bit_cast(float, hu.x << 16);
  hx[1] = __builtin_bit_cast(float, hu.x & 0xffff0000u);
  hx[2] = __builtin_bit_cast(float, hu.y << 16);
  hx[3] = __builtin_bit_cast(float, hu.y & 0xffff0000u);
  float wv[8];
  load8(lw3 + (size_t)k0 * 2, wv);
  float p0 = 0.f, p1 = 0.f;
#pragma unroll
  for (int i = 0; i < 4; i++) {
    p0 = fmaf(hx[i], wv[2 * i], p0);
    p1 = fmaf(hx[i], wv[2 * i + 1], p1);
  }
#pragma unroll
  for (int off = 32; off >= 1; off >>= 1) {
    p0 += __shfl_xor(p0, off);
    p1 += __shfl_xor(p1, off);
  }
  if (lane == 0) {
    float l0 = p0 + b2f(lb3[0]);
    float l1 = p1 + b2f(lb3[1]);
    float mx = fmaxf(l0, l1);
    float q0 = __expf(l0 - mx), q1 = __expf(l1 - mx);
    float si = 1.f / (q0 + q1);
    out[row * 2 + 0] = l0;
    out[row * 2 + 1] = l1;
    out[2 * n + row * 2 + 0] = q0 * si;
    out[2 * n + row * 2 + 1] = q1 * si;
  }
}

extern "C" void kernel_launch(void* const* d_in, const int* in_sizes, int n_in,
                              void* d_out, int out_size, void* d_ws, size_t ws_size,
                              hipStream_t stream) {
  (void)in_sizes; (void)n_in; (void)out_size; (void)ws_size;
  const void* x_raw = d_in[0];
  const void* ei_raw = d_in[1];
  const void *wl[4], *bl[4], *wr[4], *br[4], *att[4], *bg[4];
  for (int i = 0; i < 4; i++) {
    wl[i] = d_in[2 + i * 6 + 0];
    bl[i] = d_in[2 + i * 6 + 1];
    wr[i] = d_in[2 + i * 6 + 2];
    br[i] = d_in[2 + i * 6 + 3];
    att[i] = d_in[2 + i * 6 + 4];
    bg[i] = d_in[2 + i * 6 + 5];
  }
  const void* lw1 = d_in[26];
  const void* lb1 = d_in[27];
  const void* lw2 = d_in[28];
  const void* lb2 = d_in[29];
  const void* lw3 = d_in[30];
  const void* lb3 = d_in[31];

  size_t off = 0;
  auto alloc = [&](size_t bytes) -> void* {
    off = (off + 255) & ~(size_t)255;
    void* p = (char*)d_ws + off;
    off += bytes;
    return p;
  };
  int* flags = (int*)alloc(8);
  int* esrc = (int*)alloc(NE * 4);
  int* edst = (int*)alloc(NE * 4);
  int* counts = (int*)alloc(NN * 4);
  int* rowptr = (int*)alloc((NN + 1) * 4);
  int* cursor = (int*)alloc(NN * 4);
  int* col = (int*)alloc((NE + NN) * 4);
  u16* vec = (u16*)alloc(20 * 512 * 2);  // 20 slots of 512 bf16
  u16 *wlT[4], *wrT[4];
  wlT[0] = (u16*)alloc((size_t)512 * 1024 * 2);
  wrT[0] = (u16*)alloc((size_t)512 * 1024 * 2);
  for (int l = 1; l < 4; l++) {
    wlT[l] = (u16*)alloc((size_t)512 * 512 * 2);
    wrT[l] = (u16*)alloc((size_t)512 * 512 * 2);
  }
  u16* lw1T = (u16*)alloc((size_t)512 * 512 * 2);
  u16* lw2T = (u16*)alloc((size_t)256 * 512 * 2);
  u16* xc = (u16*)alloc((size_t)NN * DIN_ * 2);  // canonical x (also reused as a feature buffer)
  u16* b0 = (u16*)alloc((size_t)NN * HH * 2);
  u16* b1 = (u16*)alloc((size_t)NN * HH * 2);

  // --- probe dtypes ---
  k_probe<<<1, 256, 0, stream>>>((const u16*)x_raw, (const u32*)ei_raw, flags);

  // --- canonicalize ---
  k_cvt_edges<<<(NE + 255) / 256, 256, 0, stream>>>(ei_raw, esrc, edst, flags);
  k_cvt_x<<<2048, 256, 0, stream>>>(x_raw, xc, NN * DIN_, flags);
  VecCvt vc;
  u16* vp[20];
  for (int t = 0; t < 20; t++) vp[t] = vec + t * 512;
  for (int l = 0; l < 4; l++) {
    vc.in[l * 4 + 0] = bl[l];  vc.n[l * 4 + 0] = 512;
    vc.in[l * 4 + 1] = br[l];  vc.n[l * 4 + 1] = 512;
    vc.in[l * 4 + 2] = att[l]; vc.n[l * 4 + 2] = 512;
    vc.in[l * 4 + 3] = bg[l];  vc.n[l * 4 + 3] = 512;
  }
  vc.in[16] = lb1; vc.n[16] = 512;
  vc.in[17] = lb2; vc.n[17] = 256;
  vc.in[18] = lw3; vc.n[18] = 512;
  vc.in[19] = lb3; vc.n[19] = 2;
  for (int t = 0; t < 20; t++) vc.out[t] = vp[t];
  k_cvt_vecs<<<20, 256, 0, stream>>>(vc, flags);

  // --- CSR by dst ---
  hipMemsetAsync(counts, 0, NN * 4, stream);
  int ET = NE + NN;
  k_count<<<(ET + 255) / 256, 256, 0, stream>>>(edst, counts, NE, NN);
  k_scan<<<1, 1024, 0, stream>>>(counts, rowptr, NN);
  k_copy<<<(NN + 255) / 256, 256, 0, stream>>>(rowptr, cursor, NN);
  k_scatter<<<(ET + 255) / 256, 256, 0, stream>>>(esrc, edst, cursor, col, NE, NN);

  // --- weight transposes (+dtype cvt) ---
  dim3 tb(32, 8);
  k_trc<<<dim3(16, 32), tb, 0, stream>>>(wl[0], wlT[0], 1024, 512, flags);
  k_trc<<<dim3(16, 32), tb, 0, stream>>>(wr[0], wrT[0], 1024, 512, flags);
  for (int l = 1; l < 4; l++) {
    k_trc<<<dim3(16, 16), tb, 0, stream>>>(wl[l], wlT[l], 512, 512, flags);
    k_trc<<<dim3(16, 16), tb, 0, stream>>>(wr[l], wrT[l], 512, 512, flags);
  }
  k_trc<<<dim3(16, 16), tb, 0, stream>>>(lw1, lw1T, 512, 512, flags);
  k_trc<<<dim3(8, 16), tb, 0, stream>>>(lw2, lw2T, 512, 256, flags);

  const int tiles_m = (NN + 63) / 64;  // 157
  auto gemm = [&](const u16* A, const u16* Bt, const u16* bias, u16* C, int M, int Nn, int K, int act) {
    int waves = tiles_m * (Nn >> 6);
    int blocks = (waves * 64 + 255) / 256;
    k_gemm<<<blocks, 256, 0, stream>>>(A, Bt, bias, C, M, Nn, K, act, waves);
  };
  auto attn = [&](const u16* xl_, const u16* xr_, int l, u16* out_) {
    k_attn<<<(NN * 64 + 255) / 256, 256, 0, stream>>>(xl_, xr_, vp[l * 4 + 2], vp[l * 4 + 3],
                                                      rowptr, col, out_, NN);
  };

  // Layer 1: cur = xc [K=1024]
  gemm(xc, wlT[0], vp[0 * 4 + 0], b0, NN, HH, DIN_, 0);
  gemm(xc, wrT[0], vp[0 * 4 + 1], b1, NN, HH, DIN_, 0);
  attn(b0, b1, 0, b1);  // h1 -> b1 (in-place on xr)
  // Layer 2: cur = b1
  gemm(b1, wlT[1], vp[1 * 4 + 0], b0, NN, HH, HH, 0);
  gemm(b1, wrT[1], vp[1 * 4 + 1], xc, NN, HH, HH, 0);
  attn(b0, xc, 1, xc);  // h2 -> xc
  // Layer 3: cur = xc
  gemm(xc, wlT[2], vp[2 * 4 + 0], b0, NN, HH, HH, 0);
  gemm(xc, wrT[2], vp[2 * 4 + 1], b1, NN, HH, HH, 0);
  attn(b0, b1, 2, b1);  // h3 -> b1
  // Layer 4: cur = b1
  gemm(b1, wlT[3], vp[3 * 4 + 0], b0, NN, HH, HH, 0);
  gemm(b1, wrT[3], vp[3 * 4 + 1], xc, NN, HH, HH, 0);
  attn(b0, xc, 3, xc);  // h4 -> xc

  // MLP head
  gemm(xc, lw1T, vp[16], b0, NN, 512, 512, 1);
  gemm(b0, lw2T, vp[17], b1, NN, 256, 512, 1);
  k_head<<<(NN * 64 + 255) / 256, 256, 0, stream>>>(b1, vp[18], vp[19], (float*)d_out, NN);
}

// Round 5
// 553.948 us; speedup vs baseline: 1.4326x; 1.4326x over previous
//
#include <hip/hip_runtime.h>
#include <cstdint>

#define NN 10000
#define NE 80000
#define DIN_ 1024
#define HH 512

typedef __attribute__((ext_vector_type(8))) short bf16x8;
typedef __attribute__((ext_vector_type(4))) float f32x4;
typedef unsigned short u16;
typedef unsigned int u32;

static __device__ __forceinline__ float b2f(u16 u) {
  u32 i = ((u32)u) << 16;
  return __builtin_bit_cast(float, i);
}
static __device__ __forceinline__ u16 f2b(float f) {
  u32 i = __builtin_bit_cast(u32, f);
  u32 r = (i + 0x7fffu + ((i >> 16) & 1u)) >> 16;
  return (u16)r;
}
static __device__ __forceinline__ void load8(const u16* p, float* f) {
  uint4 u = *(const uint4*)p;
  f[0] = __builtin_bit_cast(float, u.x << 16);
  f[1] = __builtin_bit_cast(float, u.x & 0xffff0000u);
  f[2] = __builtin_bit_cast(float, u.y << 16);
  f[3] = __builtin_bit_cast(float, u.y & 0xffff0000u);
  f[4] = __builtin_bit_cast(float, u.z << 16);
  f[5] = __builtin_bit_cast(float, u.z & 0xffff0000u);
  f[6] = __builtin_bit_cast(float, u.w << 16);
  f[7] = __builtin_bit_cast(float, u.w & 0xffff0000u);
}

// async global->LDS, 16B per lane; LDS dest = wave-uniform base + lane*16
#define ASYNC_CP16(gp, lp)                                                     \
  __builtin_amdgcn_global_load_lds((__attribute__((address_space(1))) void*)(gp), \
                                   (__attribute__((address_space(3))) void*)(lp), \
                                   16, 0, 0)

// ---------------- dtype probe ----------------
__global__ void k_probe(const u16* xw, const u32* ew, int* flags) {
  __shared__ int c0, c1;
  if (threadIdx.x == 0) { c0 = 0; c1 = 0; }
  __syncthreads();
  int t = threadIdx.x;
  int bad = 0;
  for (int i = t; i < 2048; i += 256) {
    u32 e = (xw[i] >> 7) & 0xFFu;
    if (e >= 140u) bad++;
  }
  if (bad) atomicAdd(&c0, bad);
  int z = 0;
  for (int i = t; i < 512; i += 256)
    if (ew[2 * i + 1] == 0u) z++;
  if (z) atomicAdd(&c1, z);
  __syncthreads();
  if (t == 0) {
    flags[0] = (c0 > 64) ? 1 : 0;   // 1 = fp32 inputs
    flags[1] = (c1 > 200) ? 1 : 0;  // 1 = int64 edges
  }
}

// ---------------- canonicalization ----------------
__global__ void k_cvt_edges(const void* ei, int* s, int* d, const int* flags) {
  int i = blockIdx.x * blockDim.x + threadIdx.x;
  if (i >= NE) return;
  if (flags[1]) {
    const long long* p = (const long long*)ei;
    s[i] = (int)p[i];
    d[i] = (int)p[NE + i];
  } else {
    const int* p = (const int*)ei;
    s[i] = p[i];
    d[i] = p[NE + i];
  }
}

__global__ void k_cvt_x(const void* in, u16* out, int n, const int* flags) {
  int f = flags[0];
  for (int i = blockIdx.x * blockDim.x + threadIdx.x; i < n; i += gridDim.x * blockDim.x)
    out[i] = f ? f2b(((const float*)in)[i]) : ((const u16*)in)[i];
}

struct VecCvt {
  const void* in[20];
  u16* out[20];
  int n[20];
};
__global__ void k_cvt_vecs(VecCvt a, const int* flags) {
  int tsel = blockIdx.x;
  int f = flags[0];
  int n = a.n[tsel];
  const void* in = a.in[tsel];
  u16* out = a.out[tsel];
  for (int i = threadIdx.x; i < n; i += 256)
    out[i] = f ? f2b(((const float*)in)[i]) : ((const u16*)in)[i];
}

// fused dtype-convert + transpose: in [K,N] -> out bf16 [N,K]
__global__ void k_trc(const void* in, u16* out, int K, int N, const int* flags) {
  __shared__ u16 t[32][33];
  int f = flags[0];
  int n0 = blockIdx.x * 32, k0 = blockIdx.y * 32;
  int tx = threadIdx.x, ty = threadIdx.y;
  for (int r = ty; r < 32; r += 8) {
    size_t idx = (size_t)(k0 + r) * N + n0 + tx;
    t[r][tx] = f ? f2b(((const float*)in)[idx]) : ((const u16*)in)[idx];
  }
  __syncthreads();
  for (int r = ty; r < 32; r += 8) out[(size_t)(n0 + r) * K + k0 + tx] = t[tx][r];
}

// ---------------- CSR build ----------------
__global__ void k_count(const int* dst, int* counts, int E, int n) {
  int i = blockIdx.x * blockDim.x + threadIdx.x;
  if (i < E) atomicAdd(&counts[dst[i]], 1);
  else if (i < E + n) atomicAdd(&counts[i - E], 1);
}

__global__ void k_scan(const int* counts, int* rowptr, int n) {
  __shared__ int lds[1024];
  __shared__ int carry;
  int t = threadIdx.x;
  if (t == 0) { carry = 0; rowptr[0] = 0; }
  __syncthreads();
  for (int base = 0; base < n; base += 1024) {
    int v = (base + t < n) ? counts[base + t] : 0;
    lds[t] = v;
    __syncthreads();
    for (int off = 1; off < 1024; off <<= 1) {
      int x = (t >= off) ? lds[t - off] : 0;
      __syncthreads();
      lds[t] += x;
      __syncthreads();
    }
    if (base + t < n) rowptr[base + t + 1] = lds[t] + carry;
    __syncthreads();
    if (t == 1023) carry += lds[1023];
    __syncthreads();
  }
}

__global__ void k_copy(const int* a, int* b, int n) {
  int i = blockIdx.x * blockDim.x + threadIdx.x;
  if (i < n) b[i] = a[i];
}

__global__ void k_scatter(const int* src, const int* dst, int* cursor, int* col, int E, int n) {
  int i = blockIdx.x * blockDim.x + threadIdx.x;
  if (i < E) {
    int p = atomicAdd(&cursor[dst[i]], 1);
    col[p] = src[i];
  } else if (i < E + n) {
    int v = i - E;
    int p = atomicAdd(&cursor[v], 1);
    col[p] = v;
  }
}

// ---------------- 128x128 block-tile MFMA GEMM (m97 structure) ----------------
// C[M,N](stride N) = A[M,K](stride lda) @ Bt[N,K]^T + bias; 4 waves, each 64x64.
__global__ __launch_bounds__(256) void k_gemm128(const u16* __restrict__ A, int lda,
                                                 const u16* __restrict__ Bt,
                                                 const u16* __restrict__ bias,
                                                 u16* __restrict__ C,
                                                 int M, int N, int K, int act) {
  __shared__ u16 sA[128 * 32];
  __shared__ u16 sB[128 * 32];
  int t = threadIdx.x;
  int wave = t >> 6, lane = t & 63;
  int m0 = blockIdx.y << 7, n0 = blockIdx.x << 7;

  // staging: chunk c = q*256+t covers row c>>2, kchunk c&3; LDS u16 off = c*8
  int srow = t >> 2, sk = (t & 3) * 8;
  int ar0 = m0 + srow;       ar0 = ar0 < M ? ar0 : M - 1;
  int ar1 = m0 + 64 + srow;  ar1 = ar1 < M ? ar1 : M - 1;
  const u16* agp0 = A + (size_t)ar0 * lda + sk;
  const u16* agp1 = A + (size_t)ar1 * lda + sk;
  const u16* bgp0 = Bt + (size_t)(n0 + srow) * K + sk;
  const u16* bgp1 = Bt + (size_t)(n0 + 64 + srow) * K + sk;
  u16* la0 = sA + t * 8;
  u16* la1 = sA + 2048 + t * 8;
  u16* lb0 = sB + t * 8;
  u16* lb1 = sB + 2048 + t * 8;

  // fragment addresses: wave covers rows wm..wm+63, cols wn..wn+63
  int wm = (wave >> 1) << 6, wn = (wave & 1) << 6;
  int lr = lane & 15, lko = (lane >> 4) << 3;  // u16 offset in 32-wide row

  f32x4 acc[4][4];
#pragma unroll
  for (int i = 0; i < 4; i++)
#pragma unroll
    for (int j = 0; j < 4; j++) acc[i][j] = (f32x4){0.f, 0.f, 0.f, 0.f};

  for (int k0 = 0; k0 < K; k0 += 32) {
    ASYNC_CP16(agp0 + k0, la0);
    ASYNC_CP16(agp1 + k0, la1);
    ASYNC_CP16(bgp0 + k0, lb0);
    ASYNC_CP16(bgp1 + k0, lb1);
    __syncthreads();  // drains vmcnt (global_load_lds) before reads
    bf16x8 a[4], b[4];
#pragma unroll
    for (int i = 0; i < 4; i++) a[i] = *(const bf16x8*)(sA + (wm + i * 16 + lr) * 32 + lko);
#pragma unroll
    for (int j = 0; j < 4; j++) b[j] = *(const bf16x8*)(sB + (wn + j * 16 + lr) * 32 + lko);
#pragma unroll
    for (int i = 0; i < 4; i++)
#pragma unroll
      for (int j = 0; j < 4; j++)
        acc[i][j] = __builtin_amdgcn_mfma_f32_16x16x32_bf16(a[i], b[j], acc[i][j], 0, 0, 0);
    __syncthreads();  // all reads done before next stage overwrites
  }

  int rbase = (lane >> 4) << 2;
#pragma unroll
  for (int j = 0; j < 4; j++) {
    int colc = n0 + wn + j * 16 + lr;
    float bv = b2f(bias[colc]);
#pragma unroll
    for (int i = 0; i < 4; i++) {
#pragma unroll
      for (int r = 0; r < 4; r++) {
        int row = m0 + wm + i * 16 + rbase + r;
        if (row < M) {
          float v = acc[i][j][r] + bv;
          if (act) v = fmaxf(v, 0.f);
          C[(size_t)row * N + colc] = f2b(v);
        }
      }
    }
  }
}

// ---------------- GATv2 attention on fused [xl|xr] buffer (stride 1024) ----------------
// xl(j) = xlr[j*1024 + h]; xr(node)/out = xlr[node*1024 + 512 + h] (in-place over xr half)
__global__ __launch_bounds__(256) void k_attn2(u16* __restrict__ xlr,
                                               const u16* __restrict__ att, const u16* __restrict__ bias,
                                               const int* __restrict__ rowptr, const int* __restrict__ col,
                                               int n) {
  int node = (blockIdx.x * 256 + threadIdx.x) >> 6;
  if (node >= n) return;
  int lane = threadIdx.x & 63;
  int h0 = lane * 8;
  float a[8], r[8];
  load8(att + h0, a);
  load8(xlr + (size_t)node * 1024 + 512 + h0, r);
  int e0 = rowptr[node], e1 = rowptr[node + 1];

  float m = -3e38f, s = 0.f;
  for (int e = e0; e < e1; e++) {
    int j = col[e];
    float xv[8];
    load8(xlr + (size_t)j * 1024 + h0, xv);
    float part = 0.f;
#pragma unroll
    for (int i = 0; i < 8; i++) {
      float z = xv[i] + r[i];
      z = z > 0.f ? z : 0.2f * z;
      part = fmaf(a[i], z, part);
    }
#pragma unroll
    for (int off = 32; off >= 1; off >>= 1) part += __shfl_xor(part, off);
    float mn = fmaxf(m, part);
    s = s * __expf(m - mn) + __expf(part - mn);
    m = mn;
  }
  float inv = 1.f / (s + 1e-16f);

  float acc[8] = {0.f, 0.f, 0.f, 0.f, 0.f, 0.f, 0.f, 0.f};
  for (int e = e0; e < e1; e++) {
    int j = col[e];
    float xv[8];
    load8(xlr + (size_t)j * 1024 + h0, xv);
    float part = 0.f;
#pragma unroll
    for (int i = 0; i < 8; i++) {
      float z = xv[i] + r[i];
      z = z > 0.f ? z : 0.2f * z;
      part = fmaf(a[i], z, part);
    }
#pragma unroll
    for (int off = 32; off >= 1; off >>= 1) part += __shfl_xor(part, off);
    float w = __expf(part - m) * inv;
#pragma unroll
    for (int i = 0; i < 8; i++) acc[i] = fmaf(w, xv[i], acc[i]);
  }

  float bv[8];
  load8(bias + h0, bv);
  uint4 o;
  u32 p[8];
#pragma unroll
  for (int i = 0; i < 8; i++) {
    float v = acc[i] + bv[i];
    v = fmaxf(v, 0.f);
    p[i] = f2b(v);
  }
  o.x = p[0] | (p[1] << 16);
  o.y = p[2] | (p[3] << 16);
  o.z = p[4] | (p[5] << 16);
  o.w = p[6] | (p[7] << 16);
  *(uint4*)(xlr + (size_t)node * 1024 + 512 + h0) = o;
}

// ---------------- final linear (256->2) + softmax; fp32 out ----------------
__global__ __launch_bounds__(256) void k_head(const u16* __restrict__ h2, const u16* __restrict__ lw3,
                                              const u16* __restrict__ lb3, float* __restrict__ out, int n) {
  int row = (blockIdx.x * 256 + threadIdx.x) >> 6;
  if (row >= n) return;
  int lane = threadIdx.x & 63;
  int k0 = lane * 4;
  const u16* hp = h2 + (size_t)row * 256 + k0;
  uint2 hu = *(const uint2*)hp;
  float hx[4];
  hx[0] = __builtin_bit_cast(float, hu.x << 16);
  hx[1] = __builtin_bit_cast(float, hu.x & 0xffff0000u);
  hx[2] = __builtin_bit_cast(float, hu.y << 16);
  hx[3] = __builtin_bit_cast(float, hu.y & 0xffff0000u);
  float wv[8];
  load8(lw3 + (size_t)k0 * 2, wv);
  float p0 = 0.f, p1 = 0.f;
#pragma unroll
  for (int i = 0; i < 4; i++) {
    p0 = fmaf(hx[i], wv[2 * i], p0);
    p1 = fmaf(hx[i], wv[2 * i + 1], p1);
  }
#pragma unroll
  for (int off = 32; off >= 1; off >>= 1) {
    p0 += __shfl_xor(p0, off);
    p1 += __shfl_xor(p1, off);
  }
  if (lane == 0) {
    float l0 = p0 + b2f(lb3[0]);
    float l1 = p1 + b2f(lb3[1]);
    float mx = fmaxf(l0, l1);
    float q0 = __expf(l0 - mx), q1 = __expf(l1 - mx);
    float si = 1.f / (q0 + q1);
    out[row * 2 + 0] = l0;
    out[row * 2 + 1] = l1;
    out[2 * n + row * 2 + 0] = q0 * si;
    out[2 * n + row * 2 + 1] = q1 * si;
  }
}

extern "C" void kernel_launch(void* const* d_in, const int* in_sizes, int n_in,
                              void* d_out, int out_size, void* d_ws, size_t ws_size,
                              hipStream_t stream) {
  (void)in_sizes; (void)n_in; (void)out_size; (void)ws_size;
  const void* x_raw = d_in[0];
  const void* ei_raw = d_in[1];
  const void *wl[4], *bl[4], *wr[4], *br[4], *att[4], *bg[4];
  for (int i = 0; i < 4; i++) {
    wl[i] = d_in[2 + i * 6 + 0];
    bl[i] = d_in[2 + i * 6 + 1];
    wr[i] = d_in[2 + i * 6 + 2];
    br[i] = d_in[2 + i * 6 + 3];
    att[i] = d_in[2 + i * 6 + 4];
    bg[i] = d_in[2 + i * 6 + 5];
  }
  const void* lw1 = d_in[26];
  const void* lb1 = d_in[27];
  const void* lw2 = d_in[28];
  const void* lb2 = d_in[29];
  const void* lw3 = d_in[30];
  const void* lb3 = d_in[31];

  size_t off = 0;
  auto alloc = [&](size_t bytes) -> void* {
    off = (off + 255) & ~(size_t)255;
    void* p = (char*)d_ws + off;
    off += bytes;
    return p;
  };
  int* flags = (int*)alloc(8);
  int* esrc = (int*)alloc(NE * 4);
  int* edst = (int*)alloc(NE * 4);
  int* counts = (int*)alloc(NN * 4);
  int* rowptr = (int*)alloc((NN + 1) * 4);
  int* cursor = (int*)alloc(NN * 4);
  int* col = (int*)alloc((NE + NN) * 4);
  u16* cb = (u16*)alloc(4 * 1024 * 2);       // combined [bl;br] per layer
  u16* attv = (u16*)alloc(4 * 512 * 2);      // att vectors
  u16* bgv = (u16*)alloc(4 * 512 * 2);       // GAT output biases
  u16* lb1v = (u16*)alloc(512 * 2);
  u16* lb2v = (u16*)alloc(256 * 2);
  u16* lw3v = (u16*)alloc(512 * 2);
  u16* lb3v = (u16*)alloc(2 * 2);
  u16* comb0 = (u16*)alloc((size_t)1024 * 1024 * 2);  // [wlT0;wrT0]
  u16* combL[4];
  combL[0] = comb0;
  for (int l = 1; l < 4; l++) combL[l] = (u16*)alloc((size_t)1024 * 512 * 2);
  u16* lw1T = (u16*)alloc((size_t)512 * 512 * 2);
  u16* lw2T = (u16*)alloc((size_t)256 * 512 * 2);
  u16* xc = (u16*)alloc((size_t)NN * DIN_ * 2);   // canonical x; later reused for MLP bufs
  u16* X0 = (u16*)alloc((size_t)NN * 1024 * 2);   // fused [xl|xr] ping
  u16* X1 = (u16*)alloc((size_t)NN * 1024 * 2);   // pong
  u16* mlp1 = xc;                                  // [NN,512] (xc dead after layer-1 GEMM)
  u16* mlp2 = xc + (size_t)NN * 512;               // [NN,256]

  // --- probe + canonicalize ---
  k_probe<<<1, 256, 0, stream>>>((const u16*)x_raw, (const u32*)ei_raw, flags);
  k_cvt_edges<<<(NE + 255) / 256, 256, 0, stream>>>(ei_raw, esrc, edst, flags);
  k_cvt_x<<<2048, 256, 0, stream>>>(x_raw, xc, NN * DIN_, flags);
  VecCvt vc;
  for (int l = 0; l < 4; l++) {
    vc.in[l * 4 + 0] = bl[l];  vc.out[l * 4 + 0] = cb + l * 1024;        vc.n[l * 4 + 0] = 512;
    vc.in[l * 4 + 1] = br[l];  vc.out[l * 4 + 1] = cb + l * 1024 + 512;  vc.n[l * 4 + 1] = 512;
    vc.in[l * 4 + 2] = att[l]; vc.out[l * 4 + 2] = attv + l * 512;       vc.n[l * 4 + 2] = 512;
    vc.in[l * 4 + 3] = bg[l];  vc.out[l * 4 + 3] = bgv + l * 512;        vc.n[l * 4 + 3] = 512;
  }
  vc.in[16] = lb1; vc.out[16] = lb1v; vc.n[16] = 512;
  vc.in[17] = lb2; vc.out[17] = lb2v; vc.n[17] = 256;
  vc.in[18] = lw3; vc.out[18] = lw3v; vc.n[18] = 512;
  vc.in[19] = lb3; vc.out[19] = lb3v; vc.n[19] = 2;
  k_cvt_vecs<<<20, 256, 0, stream>>>(vc, flags);

  // --- CSR by dst ---
  hipMemsetAsync(counts, 0, NN * 4, stream);
  int ET = NE + NN;
  k_count<<<(ET + 255) / 256, 256, 0, stream>>>(edst, counts, NE, NN);
  k_scan<<<1, 1024, 0, stream>>>(counts, rowptr, NN);
  k_copy<<<(NN + 255) / 256, 256, 0, stream>>>(rowptr, cursor, NN);
  k_scatter<<<(ET + 255) / 256, 256, 0, stream>>>(esrc, edst, cursor, col, NE, NN);

  // --- weight transposes (+dtype cvt), stacked [wlT;wrT] ---
  dim3 tb(32, 8);
  k_trc<<<dim3(16, 32), tb, 0, stream>>>(wl[0], comb0, 1024, 512, flags);
  k_trc<<<dim3(16, 32), tb, 0, stream>>>(wr[0], comb0 + (size_t)512 * 1024, 1024, 512, flags);
  for (int l = 1; l < 4; l++) {
    k_trc<<<dim3(16, 16), tb, 0, stream>>>(wl[l], combL[l], 512, 512, flags);
    k_trc<<<dim3(16, 16), tb, 0, stream>>>(wr[l], combL[l] + (size_t)512 * 512, 512, 512, flags);
  }
  k_trc<<<dim3(16, 16), tb, 0, stream>>>(lw1, lw1T, 512, 512, flags);
  k_trc<<<dim3(8, 16), tb, 0, stream>>>(lw2, lw2T, 512, 256, flags);

  auto gemm = [&](const u16* A, int lda, const u16* Bt, const u16* bias, u16* C,
                  int M, int Nn, int K, int act) {
    dim3 grid(Nn >> 7, (M + 127) >> 7);
    k_gemm128<<<grid, 256, 0, stream>>>(A, lda, Bt, bias, C, M, Nn, K, act);
  };
  auto attn = [&](u16* xlr, int l) {
    k_attn2<<<(NN * 64 + 255) / 256, 256, 0, stream>>>(xlr, attv + l * 512, bgv + l * 512,
                                                       rowptr, col, NN);
  };

  // Layer 1: [xl|xr] = xc @ comb0 (K=1024, N=1024)
  gemm(xc, 1024, comb0, cb + 0 * 1024, X0, NN, 1024, 1024, 0);
  attn(X0, 0);  // h1 -> X0 xr-half
  // Layer 2
  gemm(X0 + 512, 1024, combL[1], cb + 1 * 1024, X1, NN, 1024, 512, 0);
  attn(X1, 1);  // h2 -> X1 xr-half
  // Layer 3
  gemm(X1 + 512, 1024, combL[2], cb + 2 * 1024, X0, NN, 1024, 512, 0);
  attn(X0, 2);  // h3 -> X0 xr-half
  // Layer 4
  gemm(X0 + 512, 1024, combL[3], cb + 3 * 1024, X1, NN, 1024, 512, 0);
  attn(X1, 3);  // h4 -> X1 xr-half

  // MLP head (xc reusable now)
  gemm(X1 + 512, 1024, lw1T, lb1v, mlp1, NN, 512, 512, 1);
  gemm(mlp1, 512, lw2T, lb2v, mlp2, NN, 256, 512, 1);
  k_head<<<(NN * 64 + 255) / 256, 256, 0, stream>>>(mlp2, lw3v, lb3v, (float*)d_out, NN);
}

// Round 6
// 446.214 us; speedup vs baseline: 1.7785x; 1.2414x over previous
//
#include <hip/hip_runtime.h>
#include <cstdint>

#define NN 10000
#define NE 80000
#define DIN_ 1024
#define HH 512

typedef __attribute__((ext_vector_type(8))) short bf16x8;
typedef __attribute__((ext_vector_type(4))) float f32x4;
typedef unsigned short u16;
typedef unsigned int u32;

static __device__ __forceinline__ float b2f(u16 u) {
  u32 i = ((u32)u) << 16;
  return __builtin_bit_cast(float, i);
}
static __device__ __forceinline__ u16 f2b(float f) {
  u32 i = __builtin_bit_cast(u32, f);
  u32 r = (i + 0x7fffu + ((i >> 16) & 1u)) >> 16;
  return (u16)r;
}
static __device__ __forceinline__ void unpack8(uint4 u, float* f) {
  f[0] = __builtin_bit_cast(float, u.x << 16);
  f[1] = __builtin_bit_cast(float, u.x & 0xffff0000u);
  f[2] = __builtin_bit_cast(float, u.y << 16);
  f[3] = __builtin_bit_cast(float, u.y & 0xffff0000u);
  f[4] = __builtin_bit_cast(float, u.z << 16);
  f[5] = __builtin_bit_cast(float, u.z & 0xffff0000u);
  f[6] = __builtin_bit_cast(float, u.w << 16);
  f[7] = __builtin_bit_cast(float, u.w & 0xffff0000u);
}
static __device__ __forceinline__ void load8(const u16* p, float* f) { unpack8(*(const uint4*)p, f); }

#define ASYNC_CP16(gp, lp)                                                        \
  __builtin_amdgcn_global_load_lds((__attribute__((address_space(1))) void*)(gp), \
                                   (__attribute__((address_space(3))) void*)(lp), \
                                   16, 0, 0)

// per-block dtype flags (no cross-kernel dependency)
static __device__ __forceinline__ int float_flag(const u16* xw) {
  __shared__ int c;
  if (threadIdx.x == 0) c = 0;
  __syncthreads();
  int bad = 0;
  for (int i = threadIdx.x; i < 2048; i += blockDim.x) {
    u32 e = (xw[i] >> 7) & 0xFFu;
    if (e >= 140u) bad++;  // |v|>=2^13 impossible for bf16 x~N(0,1); ~44% if fp32 words
  }
  if (bad) atomicAdd(&c, bad);
  __syncthreads();
  return c > 64;
}
static __device__ __forceinline__ int int64_flag(const u32* ew) {
  __shared__ int c;
  if (threadIdx.x == 0) c = 0;
  __syncthreads();
  int z = 0;
  for (int i = threadIdx.x; i < 256; i += blockDim.x)
    if (ew[2 * i + 1] == 0u) z++;  // int64 high words all zero
  if (z) atomicAdd(&c, z);
  __syncthreads();
  return c > 200;
}

// ---------------- edges: dtype cvt + degree count ----------------
__global__ void k_edges(const void* ei, int* esrc, int* edst, int* counts) {
  int f64 = int64_flag((const u32*)ei);
  int i = blockIdx.x * 256 + threadIdx.x;
  if (i < NE) {
    int sv, dv;
    if (f64) {
      sv = (int)((const long long*)ei)[i];
      dv = (int)((const long long*)ei)[NE + i];
    } else {
      sv = ((const int*)ei)[i];
      dv = ((const int*)ei)[NE + i];
    }
    esrc[i] = sv;
    edst[i] = dv;
    atomicAdd(&counts[dv], 1);
  } else if (i < NE + NN) {
    atomicAdd(&counts[i - NE], 1);  // self-loop
  }
}

// ---------------- scan (+ cursor = exclusive prefix) ----------------
__global__ void k_scan(const int* counts, int* rowptr, int* cursor, int n) {
  __shared__ int lds[1024];
  __shared__ int carry;
  int t = threadIdx.x;
  if (t == 0) { carry = 0; rowptr[0] = 0; }
  __syncthreads();
  for (int base = 0; base < n; base += 1024) {
    int v = (base + t < n) ? counts[base + t] : 0;
    lds[t] = v;
    __syncthreads();
    for (int off = 1; off < 1024; off <<= 1) {
      int x = (t >= off) ? lds[t - off] : 0;
      __syncthreads();
      lds[t] += x;
      __syncthreads();
    }
    if (base + t < n) {
      int inc = lds[t] + carry;
      rowptr[base + t + 1] = inc;
      cursor[base + t] = inc - v;
    }
    __syncthreads();
    if (t == 1023) carry += lds[1023];
    __syncthreads();
  }
}

__global__ void k_scatter(const int* src, const int* dst, int* cursor, int* col, int E, int n) {
  int i = blockIdx.x * blockDim.x + threadIdx.x;
  if (i < E) {
    int p = atomicAdd(&cursor[dst[i]], 1);
    col[p] = src[i];
  } else if (i < E + n) {
    int v = i - E;
    int p = atomicAdd(&cursor[v], 1);
    col[p] = v;
  }
}

// ---------------- fused conversion: x + 20 small vectors ----------------
struct CvtAll {
  const void* xin;
  u16* xout;
  const void* vin[20];
  u16* vout[20];
  int vn[20];
};
__global__ void k_convert(CvtAll a) {
  int f = float_flag((const u16*)a.xin);
  if (blockIdx.x < 1024) {
    for (int i = blockIdx.x * 256 + threadIdx.x; i < NN * DIN_; i += 1024 * 256)
      a.xout[i] = f ? f2b(((const float*)a.xin)[i]) : ((const u16*)a.xin)[i];
  } else {
    int v = blockIdx.x - 1024;
    const void* in = a.vin[v];
    u16* out = a.vout[v];
    int n = a.vn[v];
    for (int i = threadIdx.x; i < n; i += 256)
      out[i] = f ? f2b(((const float*)in)[i]) : ((const u16*)in)[i];
  }
}

// ---------------- fused transpose of all 10 weight matrices ----------------
struct TrAll {
  const void* xin;  // for flag
  const void* in[10];
  u16* out[10];
  int K[10], N[10], off[10];  // off = first blockIdx of segment
};
__global__ void k_trall(TrAll a) {
  __shared__ u16 tt[32][33];
  int f = float_flag((const u16*)a.xin);
  int b = blockIdx.x;
  int seg = 0;
#pragma unroll
  for (int i = 1; i < 10; i++)
    if (b >= a.off[i]) seg = i;
  int tl = b - a.off[seg];
  int K = a.K[seg], N = a.N[seg];
  int tiles_n = N >> 5;
  int n0 = (tl % tiles_n) << 5, k0 = (tl / tiles_n) << 5;
  const void* in = a.in[seg];
  u16* out = a.out[seg];
  int tx = threadIdx.x & 31, ty = threadIdx.x >> 5;
  for (int r = ty; r < 32; r += 8) {
    size_t idx = (size_t)(k0 + r) * N + n0 + tx;
    tt[r][tx] = f ? f2b(((const float*)in)[idx]) : ((const u16*)in)[idx];
  }
  __syncthreads();
  for (int r = ty; r < 32; r += 8) out[(size_t)(n0 + r) * K + k0 + tx] = tt[tx][r];
}

// ---------------- 128x128 block-tile MFMA GEMM, BK=64 (two m97-layout halves) ----------------
__global__ __launch_bounds__(256) void k_gemm128(const u16* __restrict__ A, int lda,
                                                 const u16* __restrict__ Bt,
                                                 const u16* __restrict__ bias,
                                                 u16* __restrict__ C,
                                                 int M, int N, int K, int act) {
  __shared__ u16 sA[2 * 128 * 32];
  __shared__ u16 sB[2 * 128 * 32];
  int t = threadIdx.x;
  int wave = t >> 6, lane = t & 63;
  int m0 = blockIdx.y << 7, n0 = blockIdx.x << 7;

  // staging: q=0..3 -> half h=q>>1 (k +0/+32), rows (q&1)*64 + (t>>2), kc=(t&3)*8
  const u16* agp[4];
  const u16* bgp[4];
  u16* la[4];
  u16* lb[4];
#pragma unroll
  for (int q = 0; q < 4; q++) {
    int h = q >> 1;
    int row = ((q & 1) << 6) + (t >> 2);
    int kc = (t & 3) * 8;
    int ra = m0 + row;
    ra = ra < M ? ra : M - 1;
    agp[q] = A + (size_t)ra * lda + h * 32 + kc;
    bgp[q] = Bt + (size_t)(n0 + row) * K + h * 32 + kc;
    int lofs = h * 4096 + (((q & 1) << 8) + t) * 8;
    la[q] = sA + lofs;
    lb[q] = sB + lofs;
  }

  int wm = (wave >> 1) << 6, wn = (wave & 1) << 6;
  int lr = lane & 15, lko = (lane >> 4) << 3;

  f32x4 acc[4][4];
#pragma unroll
  for (int i = 0; i < 4; i++)
#pragma unroll
    for (int j = 0; j < 4; j++) acc[i][j] = (f32x4){0.f, 0.f, 0.f, 0.f};

  for (int k0 = 0; k0 < K; k0 += 64) {
#pragma unroll
    for (int q = 0; q < 4; q++) ASYNC_CP16(agp[q] + k0, la[q]);
#pragma unroll
    for (int q = 0; q < 4; q++) ASYNC_CP16(bgp[q] + k0, lb[q]);
    __syncthreads();
    bf16x8 a[2][4], b[2][4];
#pragma unroll
    for (int s = 0; s < 2; s++) {
#pragma unroll
      for (int i = 0; i < 4; i++) a[s][i] = *(const bf16x8*)(sA + s * 4096 + (wm + i * 16 + lr) * 32 + lko);
#pragma unroll
      for (int j = 0; j < 4; j++) b[s][j] = *(const bf16x8*)(sB + s * 4096 + (wn + j * 16 + lr) * 32 + lko);
    }
#pragma unroll
    for (int s = 0; s < 2; s++)
#pragma unroll
      for (int i = 0; i < 4; i++)
#pragma unroll
        for (int j = 0; j < 4; j++)
          acc[i][j] = __builtin_amdgcn_mfma_f32_16x16x32_bf16(a[s][i], b[s][j], acc[i][j], 0, 0, 0);
    __syncthreads();
  }

  int rbase = (lane >> 4) << 2;
#pragma unroll
  for (int j = 0; j < 4; j++) {
    int colc = n0 + wn + j * 16 + lr;
    float bv = b2f(bias[colc]);
#pragma unroll
    for (int i = 0; i < 4; i++) {
#pragma unroll
      for (int r = 0; r < 4; r++) {
        int row = m0 + wm + i * 16 + rbase + r;
        if (row < M) {
          float v = acc[i][j][r] + bv;
          if (act) v = fmaxf(v, 0.f);
          C[(size_t)row * N + colc] = f2b(v);
        }
      }
    }
  }
}

// ---------------- single-pass GATv2 attention on fused [xl|xr] (stride 1024) ----------------
__global__ __launch_bounds__(256) void k_attn2(u16* __restrict__ xlr,
                                               const u16* __restrict__ att, const u16* __restrict__ bias,
                                               const int* __restrict__ rowptr, const int* __restrict__ col,
                                               int n) {
  int node = (blockIdx.x * 256 + threadIdx.x) >> 6;
  if (node >= n) return;
  int lane = threadIdx.x & 63;
  int h0 = lane * 8;
  float a[8], r[8];
  load8(att + h0, a);
  load8(xlr + (size_t)node * 1024 + 512 + h0, r);
  int e0 = rowptr[node], e1 = rowptr[node + 1];

  float m = -3e38f, s = 0.f;
  float acc[8] = {0.f, 0.f, 0.f, 0.f, 0.f, 0.f, 0.f, 0.f};
  uint4 raw = *(const uint4*)(xlr + (size_t)col[e0] * 1024 + h0);
  for (int e = e0; e < e1; e++) {
    int jn = col[(e + 1 < e1) ? e + 1 : e];
    float xv[8];
    unpack8(raw, xv);
    uint4 rawn = *(const uint4*)(xlr + (size_t)jn * 1024 + h0);  // prefetch next gather
    float part = 0.f;
#pragma unroll
    for (int i = 0; i < 8; i++) {
      float z = xv[i] + r[i];
      z = z > 0.f ? z : 0.2f * z;
      part = fmaf(a[i], z, part);
    }
#pragma unroll
    for (int off = 32; off >= 1; off >>= 1) part += __shfl_xor(part, off);
    float mn = fmaxf(m, part);
    float al = __expf(m - mn);   // first iter: exp(-inf) = 0
    float w = __expf(part - mn);
    s = s * al + w;
#pragma unroll
    for (int i = 0; i < 8; i++) acc[i] = fmaf(acc[i], al, w * xv[i]);
    m = mn;
    raw = rawn;
  }
  float inv = 1.f / (s + 1e-16f);

  float bv[8];
  load8(bias + h0, bv);
  uint4 o;
  u32 p[8];
#pragma unroll
  for (int i = 0; i < 8; i++) {
    float v = fmaf(acc[i], inv, bv[i]);
    v = fmaxf(v, 0.f);
    p[i] = f2b(v);
  }
  o.x = p[0] | (p[1] << 16);
  o.y = p[2] | (p[3] << 16);
  o.z = p[4] | (p[5] << 16);
  o.w = p[6] | (p[7] << 16);
  *(uint4*)(xlr + (size_t)node * 1024 + 512 + h0) = o;  // in-place over xr half (safe: only own wave reads it)
}

// ---------------- final linear (256->2) + softmax; fp32 out ----------------
__global__ __launch_bounds__(256) void k_head(const u16* __restrict__ h2, const u16* __restrict__ lw3,
                                              const u16* __restrict__ lb3, float* __restrict__ out, int n) {
  int row = (blockIdx.x * 256 + threadIdx.x) >> 6;
  if (row >= n) return;
  int lane = threadIdx.x & 63;
  int k0 = lane * 4;
  uint2 hu = *(const uint2*)(h2 + (size_t)row * 256 + k0);
  float hx[4];
  hx[0] = __builtin_bit_cast(float, hu.x << 16);
  hx[1] = __builtin_bit_cast(float, hu.x & 0xffff0000u);
  hx[2] = __builtin_bit_cast(float, hu.y << 16);
  hx[3] = __builtin_bit_cast(float, hu.y & 0xffff0000u);
  float wv[8];
  load8(lw3 + (size_t)k0 * 2, wv);
  float p0 = 0.f, p1 = 0.f;
#pragma unroll
  for (int i = 0; i < 4; i++) {
    p0 = fmaf(hx[i], wv[2 * i], p0);
    p1 = fmaf(hx[i], wv[2 * i + 1], p1);
  }
#pragma unroll
  for (int off = 32; off >= 1; off >>= 1) {
    p0 += __shfl_xor(p0, off);
    p1 += __shfl_xor(p1, off);
  }
  if (lane == 0) {
    float l0 = p0 + b2f(lb3[0]);
    float l1 = p1 + b2f(lb3[1]);
    float mx = fmaxf(l0, l1);
    float q0 = __expf(l0 - mx), q1 = __expf(l1 - mx);
    float si = 1.f / (q0 + q1);
    out[row * 2 + 0] = l0;
    out[row * 2 + 1] = l1;
    out[2 * n + row * 2 + 0] = q0 * si;
    out[2 * n + row * 2 + 1] = q1 * si;
  }
}

extern "C" void kernel_launch(void* const* d_in, const int* in_sizes, int n_in,
                              void* d_out, int out_size, void* d_ws, size_t ws_size,
                              hipStream_t stream) {
  (void)in_sizes; (void)n_in; (void)out_size; (void)ws_size;
  const void* x_raw = d_in[0];
  const void* ei_raw = d_in[1];
  const void *wl[4], *bl[4], *wr[4], *br[4], *att[4], *bg[4];
  for (int i = 0; i < 4; i++) {
    wl[i] = d_in[2 + i * 6 + 0];
    bl[i] = d_in[2 + i * 6 + 1];
    wr[i] = d_in[2 + i * 6 + 2];
    br[i] = d_in[2 + i * 6 + 3];
    att[i] = d_in[2 + i * 6 + 4];
    bg[i] = d_in[2 + i * 6 + 5];
  }
  const void* lw1 = d_in[26];
  const void* lb1 = d_in[27];
  const void* lw2 = d_in[28];
  const void* lb2 = d_in[29];
  const void* lw3 = d_in[30];
  const void* lb3 = d_in[31];

  size_t off = 0;
  auto alloc = [&](size_t bytes) -> void* {
    off = (off + 255) & ~(size_t)255;
    void* p = (char*)d_ws + off;
    off += bytes;
    return p;
  };
  int* esrc = (int*)alloc(NE * 4);
  int* edst = (int*)alloc(NE * 4);
  int* counts = (int*)alloc(NN * 4);
  int* rowptr = (int*)alloc((NN + 1) * 4);
  int* cursor = (int*)alloc(NN * 4);
  int* col = (int*)alloc((NE + NN) * 4);
  u16* cb = (u16*)alloc(4 * 1024 * 2);
  u16* attv = (u16*)alloc(4 * 512 * 2);
  u16* bgv = (u16*)alloc(4 * 512 * 2);
  u16* lb1v = (u16*)alloc(512 * 2);
  u16* lb2v = (u16*)alloc(256 * 2);
  u16* lw3v = (u16*)alloc(512 * 2);
  u16* lb3v = (u16*)alloc(2 * 2);
  u16* comb0 = (u16*)alloc((size_t)1024 * 1024 * 2);
  u16* combL[4];
  combL[0] = comb0;
  for (int l = 1; l < 4; l++) combL[l] = (u16*)alloc((size_t)1024 * 512 * 2);
  u16* lw1T = (u16*)alloc((size_t)512 * 512 * 2);
  u16* lw2T = (u16*)alloc((size_t)256 * 512 * 2);
  u16* xc = (u16*)alloc((size_t)NN * DIN_ * 2);
  u16* X0 = (u16*)alloc((size_t)NN * 1024 * 2);
  u16* X1 = (u16*)alloc((size_t)NN * 1024 * 2);
  u16* mlp1 = xc;                       // xc dead after layer-1 GEMM
  u16* mlp2 = xc + (size_t)NN * 512;

  // --- CSR (flags computed per-block inside kernels) ---
  hipMemsetAsync(counts, 0, NN * 4, stream);
  int ET = NE + NN;
  k_edges<<<(ET + 255) / 256, 256, 0, stream>>>(ei_raw, esrc, edst, counts);
  k_scan<<<1, 1024, 0, stream>>>(counts, rowptr, cursor, NN);
  k_scatter<<<(ET + 255) / 256, 256, 0, stream>>>(esrc, edst, cursor, col, NE, NN);

  // --- conversions ---
  CvtAll ca;
  ca.xin = x_raw;
  ca.xout = xc;
  for (int l = 0; l < 4; l++) {
    ca.vin[l * 4 + 0] = bl[l];  ca.vout[l * 4 + 0] = cb + l * 1024;        ca.vn[l * 4 + 0] = 512;
    ca.vin[l * 4 + 1] = br[l];  ca.vout[l * 4 + 1] = cb + l * 1024 + 512;  ca.vn[l * 4 + 1] = 512;
    ca.vin[l * 4 + 2] = att[l]; ca.vout[l * 4 + 2] = attv + l * 512;       ca.vn[l * 4 + 2] = 512;
    ca.vin[l * 4 + 3] = bg[l];  ca.vout[l * 4 + 3] = bgv + l * 512;        ca.vn[l * 4 + 3] = 512;
  }
  ca.vin[16] = lb1; ca.vout[16] = lb1v; ca.vn[16] = 512;
  ca.vin[17] = lb2; ca.vout[17] = lb2v; ca.vn[17] = 256;
  ca.vin[18] = lw3; ca.vout[18] = lw3v; ca.vn[18] = 512;
  ca.vin[19] = lb3; ca.vout[19] = lb3v; ca.vn[19] = 2;
  k_convert<<<1024 + 20, 256, 0, stream>>>(ca);

  // --- all weight transposes in one launch ---
  TrAll ta;
  ta.xin = x_raw;
  const void* tin[10] = {wl[0], wr[0], wl[1], wr[1], wl[2], wr[2], wl[3], wr[3], lw1, lw2};
  u16* tout[10] = {comb0, comb0 + (size_t)512 * 1024,
                   combL[1], combL[1] + (size_t)512 * 512,
                   combL[2], combL[2] + (size_t)512 * 512,
                   combL[3], combL[3] + (size_t)512 * 512,
                   lw1T, lw2T};
  int tK[10] = {1024, 1024, 512, 512, 512, 512, 512, 512, 512, 512};
  int tN[10] = {512, 512, 512, 512, 512, 512, 512, 512, 512, 256};
  int acc_off = 0;
  for (int i = 0; i < 10; i++) {
    ta.in[i] = tin[i];
    ta.out[i] = tout[i];
    ta.K[i] = tK[i];
    ta.N[i] = tN[i];
    ta.off[i] = acc_off;
    acc_off += (tN[i] >> 5) * (tK[i] >> 5);
  }
  k_trall<<<acc_off, 256, 0, stream>>>(ta);

  auto gemm = [&](const u16* A, int lda, const u16* Bt, const u16* bias, u16* C,
                  int M, int Nn, int K, int act) {
    dim3 grid(Nn >> 7, (M + 127) >> 7);
    k_gemm128<<<grid, 256, 0, stream>>>(A, lda, Bt, bias, C, M, Nn, K, act);
  };
  auto attn = [&](u16* xlr, int l) {
    k_attn2<<<(NN * 64 + 255) / 256, 256, 0, stream>>>(xlr, attv + l * 512, bgv + l * 512,
                                                       rowptr, col, NN);
  };

  // Layer 1
  gemm(xc, 1024, comb0, cb + 0 * 1024, X0, NN, 1024, 1024, 0);
  attn(X0, 0);
  // Layer 2
  gemm(X0 + 512, 1024, combL[1], cb + 1 * 1024, X1, NN, 1024, 512, 0);
  attn(X1, 1);
  // Layer 3
  gemm(X1 + 512, 1024, combL[2], cb + 2 * 1024, X0, NN, 1024, 512, 0);
  attn(X0, 2);
  // Layer 4
  gemm(X0 + 512, 1024, combL[3], cb + 3 * 1024, X1, NN, 1024, 512, 0);
  attn(X1, 3);

  // MLP head
  gemm(X1 + 512, 1024, lw1T, lb1v, mlp1, NN, 512, 512, 1);
  gemm(mlp1, 512, lw2T, lb2v, mlp2, NN, 256, 512, 1);
  k_head<<<(NN * 64 + 255) / 256, 256, 0, stream>>>(mlp2, lw3v, lb3v, (float*)d_out, NN);
}

// Round 7
// 390.803 us; speedup vs baseline: 2.0307x; 1.1418x over previous
//
#include <hip/hip_runtime.h>
#include <cstdint>

#define NN 10000
#define NE 80000
#define DIN_ 1024
#define HH 512

typedef __attribute__((ext_vector_type(8))) short bf16x8;
typedef __attribute__((ext_vector_type(4))) float f32x4;
typedef unsigned short u16;
typedef unsigned int u32;

static __device__ __forceinline__ float b2f(u16 u) {
  u32 i = ((u32)u) << 16;
  return __builtin_bit_cast(float, i);
}
static __device__ __forceinline__ u16 f2b(float f) {
  u32 i = __builtin_bit_cast(u32, f);
  u32 r = (i + 0x7fffu + ((i >> 16) & 1u)) >> 16;
  return (u16)r;
}
static __device__ __forceinline__ void unpack8(uint4 u, float* f) {
  f[0] = __builtin_bit_cast(float, u.x << 16);
  f[1] = __builtin_bit_cast(float, u.x & 0xffff0000u);
  f[2] = __builtin_bit_cast(float, u.y << 16);
  f[3] = __builtin_bit_cast(float, u.y & 0xffff0000u);
  f[4] = __builtin_bit_cast(float, u.z << 16);
  f[5] = __builtin_bit_cast(float, u.z & 0xffff0000u);
  f[6] = __builtin_bit_cast(float, u.w << 16);
  f[7] = __builtin_bit_cast(float, u.w & 0xffff0000u);
}
static __device__ __forceinline__ void load8(const u16* p, float* f) { unpack8(*(const uint4*)p, f); }

#define ASYNC_CP16(gp, lp)                                                        \
  __builtin_amdgcn_global_load_lds((__attribute__((address_space(1))) void*)(gp), \
                                   (__attribute__((address_space(3))) void*)(lp), \
                                   16, 0, 0)

// per-block dtype flags
static __device__ __forceinline__ int float_flag(const u16* xw) {
  __shared__ int c;
  if (threadIdx.x == 0) c = 0;
  __syncthreads();
  int bad = 0;
  for (int i = threadIdx.x; i < 2048; i += blockDim.x) {
    u32 e = (xw[i] >> 7) & 0xFFu;
    if (e >= 140u) bad++;  // |v|>=2^13 impossible for bf16 x~N(0,1)
  }
  if (bad) atomicAdd(&c, bad);
  __syncthreads();
  return c > 64;
}
static __device__ __forceinline__ int int64_flag(const u32* ew) {
  __shared__ int c;
  if (threadIdx.x == 0) c = 0;
  __syncthreads();
  int z = 0;
  for (int i = threadIdx.x; i < 256; i += blockDim.x)
    if (ew[2 * i + 1] == 0u) z++;
  if (z) atomicAdd(&c, z);
  __syncthreads();
  return c > 200;
}

// ---------------- edges: dtype cvt + degree count ----------------
__global__ void k_edges(const void* ei, int* esrc, int* edst, int* counts) {
  int f64 = int64_flag((const u32*)ei);
  int i = blockIdx.x * 256 + threadIdx.x;
  if (i < NE) {
    int sv, dv;
    if (f64) {
      sv = (int)((const long long*)ei)[i];
      dv = (int)((const long long*)ei)[NE + i];
    } else {
      sv = ((const int*)ei)[i];
      dv = ((const int*)ei)[NE + i];
    }
    esrc[i] = sv;
    edst[i] = dv;
    atomicAdd(&counts[dv], 1);
  } else if (i < NE + NN) {
    atomicAdd(&counts[i - NE], 1);  // self-loop
  }
}

// ---------------- work-efficient single-block scan (512 x 20) ----------------
__global__ __launch_bounds__(512) void k_scan(const int* counts, int* rowptr, int* cursor, int n) {
  __shared__ int lds[512];
  const int PER = 20;
  int t = threadIdx.x;
  int base = t * PER;
  int v[PER];
  int sum = 0;
#pragma unroll
  for (int i = 0; i < PER; i++) {
    int idx = base + i;
    v[i] = (idx < n) ? counts[idx] : 0;
    sum += v[i];
  }
  lds[t] = sum;
  __syncthreads();
  for (int off = 1; off < 512; off <<= 1) {
    int x = (t >= off) ? lds[t - off] : 0;
    __syncthreads();
    lds[t] += x;
    __syncthreads();
  }
  int run = (t > 0) ? lds[t - 1] : 0;
#pragma unroll
  for (int i = 0; i < PER; i++) {
    int idx = base + i;
    if (idx < n) {
      cursor[idx] = run;
      run += v[i];
      rowptr[idx + 1] = run;
    }
  }
  if (t == 0) rowptr[0] = 0;
}

__global__ void k_scatter(const int* src, const int* dst, int* cursor, int* col, int E, int n) {
  int i = blockIdx.x * blockDim.x + threadIdx.x;
  if (i < E) {
    int p = atomicAdd(&cursor[dst[i]], 1);
    col[p] = src[i];
  } else if (i < E + n) {
    int v = i - E;
    int p = atomicAdd(&cursor[v], 1);
    col[p] = v;
  }
}

// ---------------- fused prep: x convert + 20 vectors + 10 weight transposes ----------------
#define XBLK 2048
struct Prep {
  const void* xin;
  u16* xout;
  const void* vin[20];
  u16* vout[20];
  int vn[20];
  const void* tin[10];
  u16* tout[10];
  int tK[10], tN[10], toff[10];
};
__global__ void k_prep(Prep a) {
  __shared__ u16 tt[32][33];
  int f = float_flag((const u16*)a.xin);
  int b = blockIdx.x;
  if (b < XBLK) {
    // x: 8 elems/thread, grid-stride over groups of 8
    const int total = NN * DIN_ / 8;
    for (int g = b * 256 + threadIdx.x; g < total; g += XBLK * 256) {
      u16 o[8];
      if (f) {
        const float* p = (const float*)a.xin + (size_t)g * 8;
#pragma unroll
        for (int i = 0; i < 8; i++) o[i] = f2b(p[i]);
      } else {
        *(uint4*)o = *((const uint4*)a.xin + g);
      }
      *((uint4*)a.xout + g) = *(const uint4*)o;
    }
  } else if (b < XBLK + 20) {
    int v = b - XBLK;
    const void* in = a.vin[v];
    u16* out = a.vout[v];
    int n = a.vn[v];
    for (int i = threadIdx.x; i < n; i += 256)
      out[i] = f ? f2b(((const float*)in)[i]) : ((const u16*)in)[i];
  } else {
    int tb = b - XBLK - 20;
    int seg = 0;
#pragma unroll
    for (int i = 1; i < 10; i++)
      if (tb >= a.toff[i]) seg = i;
    int tl = tb - a.toff[seg];
    int K = a.tK[seg], N = a.tN[seg];
    int tiles_n = N >> 5;
    int n0 = (tl % tiles_n) << 5, k0 = (tl / tiles_n) << 5;
    const void* in = a.tin[seg];
    u16* out = a.tout[seg];
    int tx = threadIdx.x & 31, ty = threadIdx.x >> 5;
    for (int r = ty; r < 32; r += 8) {
      size_t idx = (size_t)(k0 + r) * N + n0 + tx;
      tt[r][tx] = f ? f2b(((const float*)in)[idx]) : ((const u16*)in)[idx];
    }
    __syncthreads();
    for (int r = ty; r < 32; r += 8) out[(size_t)(n0 + r) * K + k0 + tx] = tt[tx][r];
  }
}

// ---------------- 128x128 MFMA GEMM, BK=64, XOR-swizzled LDS, XCD-aware mapping ----------------
// block id: id&7 = m_tile%8 (XCD); rest: n_tile (pow2 count) x m_tile_group
__global__ __launch_bounds__(256) void k_gemm128(const u16* __restrict__ A, int lda,
                                                 const u16* __restrict__ Bt,
                                                 const u16* __restrict__ bias,
                                                 u16* __restrict__ C,
                                                 int M, int N, int K, int act,
                                                 int tiles_m, int ln_tiles_n) {
  __shared__ u16 sA[2 * 128 * 32];
  __shared__ u16 sB[2 * 128 * 32];
  int id = blockIdx.x;
  int xcd = id & 7;
  int rest = id >> 3;
  int xt = rest & ((1 << ln_tiles_n) - 1);
  int yt = ((rest >> ln_tiles_n) << 3) + xcd;
  if (yt >= tiles_m) return;
  int m0 = yt << 7, n0 = xt << 7;
  int t = threadIdx.x;
  int wave = t >> 6, lane = t & 63;

  // staging: lane t -> row t>>2, SWIZZLED k-chunk (t&3)^((t>>3)&3); LDS slot = t*16B (fixed)
  int srow = t >> 2;
  int sk = ((t & 3) ^ ((t >> 3) & 3)) * 8;
  const u16* agp[4];
  const u16* bgp[4];
  u16* la[4];
  u16* lb[4];
#pragma unroll
  for (int q = 0; q < 4; q++) {
    int h = q >> 1;  // k half (+0 / +32)
    int row = ((q & 1) << 6) + srow;
    int ra = m0 + row;
    ra = ra < M ? ra : M - 1;
    agp[q] = A + (size_t)ra * lda + h * 32 + sk;
    bgp[q] = Bt + (size_t)(n0 + row) * K + h * 32 + sk;
    int lofs = h * 4096 + (((q & 1) << 8) + t) * 8;
    la[q] = sA + lofs;
    lb[q] = sB + lofs;
  }

  int wm = (wave >> 1) << 6, wn = (wave & 1) << 6;
  int lr = lane & 15;
  int kcs = (((lane >> 4) ^ ((lr >> 1) & 3))) * 8;  // swizzled fragment k-chunk

  f32x4 acc[4][4];
#pragma unroll
  for (int i = 0; i < 4; i++)
#pragma unroll
    for (int j = 0; j < 4; j++) acc[i][j] = (f32x4){0.f, 0.f, 0.f, 0.f};

  for (int k0 = 0; k0 < K; k0 += 64) {
#pragma unroll
    for (int q = 0; q < 4; q++) ASYNC_CP16(agp[q] + k0, la[q]);
#pragma unroll
    for (int q = 0; q < 4; q++) ASYNC_CP16(bgp[q] + k0, lb[q]);
    __syncthreads();
    bf16x8 a[2][4], b[2][4];
#pragma unroll
    for (int s = 0; s < 2; s++) {
#pragma unroll
      for (int i = 0; i < 4; i++) a[s][i] = *(const bf16x8*)(sA + s * 4096 + (wm + i * 16 + lr) * 32 + kcs);
#pragma unroll
      for (int j = 0; j < 4; j++) b[s][j] = *(const bf16x8*)(sB + s * 4096 + (wn + j * 16 + lr) * 32 + kcs);
    }
#pragma unroll
    for (int s = 0; s < 2; s++)
#pragma unroll
      for (int i = 0; i < 4; i++)
#pragma unroll
        for (int j = 0; j < 4; j++)
          acc[i][j] = __builtin_amdgcn_mfma_f32_16x16x32_bf16(a[s][i], b[s][j], acc[i][j], 0, 0, 0);
    __syncthreads();
  }

  int rbase = (lane >> 4) << 2;
#pragma unroll
  for (int j = 0; j < 4; j++) {
    int colc = n0 + wn + j * 16 + lr;
    float bv = b2f(bias[colc]);
#pragma unroll
    for (int i = 0; i < 4; i++) {
#pragma unroll
      for (int r = 0; r < 4; r++) {
        int row = m0 + wm + i * 16 + rbase + r;
        if (row < M) {
          float v = acc[i][j][r] + bv;
          if (act) v = fmaxf(v, 0.f);
          C[(size_t)row * N + colc] = f2b(v);
        }
      }
    }
  }
}

// ---------------- single-pass GATv2 attention, 2-edge ILP, on fused [xl|xr] ----------------
__global__ __launch_bounds__(256) void k_attn3(u16* __restrict__ xlr,
                                               const u16* __restrict__ att, const u16* __restrict__ bias,
                                               const int* __restrict__ rowptr, const int* __restrict__ col,
                                               int n) {
  int node = (blockIdx.x * 256 + threadIdx.x) >> 6;
  if (node >= n) return;
  int lane = threadIdx.x & 63;
  int h0 = lane * 8;
  float a[8], r[8];
  load8(att + h0, a);
  load8(xlr + (size_t)node * 1024 + 512 + h0, r);
  int e0 = rowptr[node], e1 = rowptr[node + 1];

  float m = -3e38f, s = 0.f;
  float acc[8] = {0.f, 0.f, 0.f, 0.f, 0.f, 0.f, 0.f, 0.f};
  int j0 = col[e0];
  int j1 = col[(e0 + 1 < e1) ? e0 + 1 : e0];
  uint4 raw0 = *(const uint4*)(xlr + (size_t)j0 * 1024 + h0);
  uint4 raw1 = *(const uint4*)(xlr + (size_t)j1 * 1024 + h0);

  for (int e = e0; e < e1; e += 2) {
    bool has2 = (e + 1 < e1);
    int jn0 = col[(e + 2 < e1) ? e + 2 : e1 - 1];
    int jn1 = col[(e + 3 < e1) ? e + 3 : e1 - 1];
    uint4 p0 = *(const uint4*)(xlr + (size_t)jn0 * 1024 + h0);  // prefetch next pair
    uint4 p1 = *(const uint4*)(xlr + (size_t)jn1 * 1024 + h0);
    float x0[8], x1[8];
    unpack8(raw0, x0);
    unpack8(raw1, x1);
    float pa = 0.f, pb = 0.f;
#pragma unroll
    for (int i = 0; i < 8; i++) {
      float z0 = x0[i] + r[i];
      z0 = z0 > 0.f ? z0 : 0.2f * z0;
      pa = fmaf(a[i], z0, pa);
      float z1 = x1[i] + r[i];
      z1 = z1 > 0.f ? z1 : 0.2f * z1;
      pb = fmaf(a[i], z1, pb);
    }
#pragma unroll
    for (int off = 32; off >= 1; off >>= 1) {
      pa += __shfl_xor(pa, off);
      pb += __shfl_xor(pb, off);
    }
    // online update edge A (skip rescale when max unchanged; branch is wave-uniform)
    if (pa > m) {
      float al = __expf(m - pa);
      s *= al;
#pragma unroll
      for (int i = 0; i < 8; i++) acc[i] *= al;
      m = pa;
    }
    {
      float w = __expf(pa - m);
      s += w;
#pragma unroll
      for (int i = 0; i < 8; i++) acc[i] = fmaf(w, x0[i], acc[i]);
    }
    if (has2) {
      if (pb > m) {
        float al = __expf(m - pb);
        s *= al;
#pragma unroll
        for (int i = 0; i < 8; i++) acc[i] *= al;
        m = pb;
      }
      float w = __expf(pb - m);
      s += w;
#pragma unroll
      for (int i = 0; i < 8; i++) acc[i] = fmaf(w, x1[i], acc[i]);
    }
    raw0 = p0;
    raw1 = p1;
  }
  float inv = 1.f / (s + 1e-16f);

  float bv[8];
  load8(bias + h0, bv);
  uint4 o;
  u32 p[8];
#pragma unroll
  for (int i = 0; i < 8; i++) {
    float v = fmaf(acc[i], inv, bv[i]);
    v = fmaxf(v, 0.f);
    p[i] = f2b(v);
  }
  o.x = p[0] | (p[1] << 16);
  o.y = p[2] | (p[3] << 16);
  o.z = p[4] | (p[5] << 16);
  o.w = p[6] | (p[7] << 16);
  *(uint4*)(xlr + (size_t)node * 1024 + 512 + h0) = o;  // in-place over xr half
}

// ---------------- final linear (256->2) + softmax; fp32 out ----------------
__global__ __launch_bounds__(256) void k_head(const u16* __restrict__ h2, const u16* __restrict__ lw3,
                                              const u16* __restrict__ lb3, float* __restrict__ out, int n) {
  int row = (blockIdx.x * 256 + threadIdx.x) >> 6;
  if (row >= n) return;
  int lane = threadIdx.x & 63;
  int k0 = lane * 4;
  uint2 hu = *(const uint2*)(h2 + (size_t)row * 256 + k0);
  float hx[4];
  hx[0] = __builtin_bit_cast(float, hu.x << 16);
  hx[1] = __builtin_bit_cast(float, hu.x & 0xffff0000u);
  hx[2] = __builtin_bit_cast(float, hu.y << 16);
  hx[3] = __builtin_bit_cast(float, hu.y & 0xffff0000u);
  float wv[8];
  load8(lw3 + (size_t)k0 * 2, wv);
  float p0 = 0.f, p1 = 0.f;
#pragma unroll
  for (int i = 0; i < 4; i++) {
    p0 = fmaf(hx[i], wv[2 * i], p0);
    p1 = fmaf(hx[i], wv[2 * i + 1], p1);
  }
#pragma unroll
  for (int off = 32; off >= 1; off >>= 1) {
    p0 += __shfl_xor(p0, off);
    p1 += __shfl_xor(p1, off);
  }
  if (lane == 0) {
    float l0 = p0 + b2f(lb3[0]);
    float l1 = p1 + b2f(lb3[1]);
    float mx = fmaxf(l0, l1);
    float q0 = __expf(l0 - mx), q1 = __expf(l1 - mx);
    float si = 1.f / (q0 + q1);
    out[row * 2 + 0] = l0;
    out[row * 2 + 1] = l1;
    out[2 * n + row * 2 + 0] = q0 * si;
    out[2 * n + row * 2 + 1] = q1 * si;
  }
}

extern "C" void kernel_launch(void* const* d_in, const int* in_sizes, int n_in,
                              void* d_out, int out_size, void* d_ws, size_t ws_size,
                              hipStream_t stream) {
  (void)in_sizes; (void)n_in; (void)out_size; (void)ws_size;
  const void* x_raw = d_in[0];
  const void* ei_raw = d_in[1];
  const void *wl[4], *bl[4], *wr[4], *br[4], *att[4], *bg[4];
  for (int i = 0; i < 4; i++) {
    wl[i] = d_in[2 + i * 6 + 0];
    bl[i] = d_in[2 + i * 6 + 1];
    wr[i] = d_in[2 + i * 6 + 2];
    br[i] = d_in[2 + i * 6 + 3];
    att[i] = d_in[2 + i * 6 + 4];
    bg[i] = d_in[2 + i * 6 + 5];
  }
  const void* lw1 = d_in[26];
  const void* lb1 = d_in[27];
  const void* lw2 = d_in[28];
  const void* lb2 = d_in[29];
  const void* lw3 = d_in[30];
  const void* lb3 = d_in[31];

  size_t off = 0;
  auto alloc = [&](size_t bytes) -> void* {
    off = (off + 255) & ~(size_t)255;
    void* p = (char*)d_ws + off;
    off += bytes;
    return p;
  };
  int* esrc = (int*)alloc(NE * 4);
  int* edst = (int*)alloc(NE * 4);
  int* counts = (int*)alloc(NN * 4);
  int* rowptr = (int*)alloc((NN + 1) * 4);
  int* cursor = (int*)alloc(NN * 4);
  int* col = (int*)alloc((NE + NN) * 4);
  u16* cb = (u16*)alloc(4 * 1024 * 2);
  u16* attv = (u16*)alloc(4 * 512 * 2);
  u16* bgv = (u16*)alloc(4 * 512 * 2);
  u16* lb1v = (u16*)alloc(512 * 2);
  u16* lb2v = (u16*)alloc(256 * 2);
  u16* lw3v = (u16*)alloc(512 * 2);
  u16* lb3v = (u16*)alloc(2 * 2);
  u16* comb0 = (u16*)alloc((size_t)1024 * 1024 * 2);
  u16* combL[4];
  combL[0] = comb0;
  for (int l = 1; l < 4; l++) combL[l] = (u16*)alloc((size_t)1024 * 512 * 2);
  u16* lw1T = (u16*)alloc((size_t)512 * 512 * 2);
  u16* lw2T = (u16*)alloc((size_t)256 * 512 * 2);
  u16* xc = (u16*)alloc((size_t)NN * DIN_ * 2);
  u16* X0 = (u16*)alloc((size_t)NN * 1024 * 2);
  u16* X1 = (u16*)alloc((size_t)NN * 1024 * 2);
  u16* mlp1 = xc;                       // xc dead after layer-1 GEMM
  u16* mlp2 = xc + (size_t)NN * 512;

  // --- CSR ---
  hipMemsetAsync(counts, 0, NN * 4, stream);
  int ET = NE + NN;
  k_edges<<<(ET + 255) / 256, 256, 0, stream>>>(ei_raw, esrc, edst, counts);
  k_scan<<<1, 512, 0, stream>>>(counts, rowptr, cursor, NN);
  k_scatter<<<(ET + 255) / 256, 256, 0, stream>>>(esrc, edst, cursor, col, NE, NN);

  // --- fused prep (x convert + vectors + weight transposes) ---
  Prep pa;
  pa.xin = x_raw;
  pa.xout = xc;
  for (int l = 0; l < 4; l++) {
    pa.vin[l * 4 + 0] = bl[l];  pa.vout[l * 4 + 0] = cb + l * 1024;        pa.vn[l * 4 + 0] = 512;
    pa.vin[l * 4 + 1] = br[l];  pa.vout[l * 4 + 1] = cb + l * 1024 + 512;  pa.vn[l * 4 + 1] = 512;
    pa.vin[l * 4 + 2] = att[l]; pa.vout[l * 4 + 2] = attv + l * 512;       pa.vn[l * 4 + 2] = 512;
    pa.vin[l * 4 + 3] = bg[l];  pa.vout[l * 4 + 3] = bgv + l * 512;        pa.vn[l * 4 + 3] = 512;
  }
  pa.vin[16] = lb1; pa.vout[16] = lb1v; pa.vn[16] = 512;
  pa.vin[17] = lb2; pa.vout[17] = lb2v; pa.vn[17] = 256;
  pa.vin[18] = lw3; pa.vout[18] = lw3v; pa.vn[18] = 512;
  pa.vin[19] = lb3; pa.vout[19] = lb3v; pa.vn[19] = 2;
  const void* tin[10] = {wl[0], wr[0], wl[1], wr[1], wl[2], wr[2], wl[3], wr[3], lw1, lw2};
  u16* tout[10] = {comb0, comb0 + (size_t)512 * 1024,
                   combL[1], combL[1] + (size_t)512 * 512,
                   combL[2], combL[2] + (size_t)512 * 512,
                   combL[3], combL[3] + (size_t)512 * 512,
                   lw1T, lw2T};
  int tK[10] = {1024, 1024, 512, 512, 512, 512, 512, 512, 512, 512};
  int tN[10] = {512, 512, 512, 512, 512, 512, 512, 512, 512, 256};
  int acc_off = 0;
  for (int i = 0; i < 10; i++) {
    pa.tin[i] = tin[i];
    pa.tout[i] = tout[i];
    pa.tK[i] = tK[i];
    pa.tN[i] = tN[i];
    pa.toff[i] = acc_off;
    acc_off += (tN[i] >> 5) * (tK[i] >> 5);
  }
  k_prep<<<XBLK + 20 + acc_off, 256, 0, stream>>>(pa);

  auto gemm = [&](const u16* A, int lda, const u16* Bt, const u16* bias, u16* C,
                  int M, int Nn, int K, int act) {
    int tiles_m = (M + 127) >> 7;                       // 79
    int tiles_n = Nn >> 7;                              // 8 / 4 / 2 (pow2)
    int ln = (tiles_n == 8) ? 3 : (tiles_n == 4) ? 2 : 1;
    int mgrp = (tiles_m + 7) >> 3;                      // 10
    int blocks = (mgrp << 3) * tiles_n;                 // XCD-swizzled 1-D grid
    k_gemm128<<<blocks, 256, 0, stream>>>(A, lda, Bt, bias, C, M, Nn, K, act, tiles_m, ln);
  };
  auto attn = [&](u16* xlr, int l) {
    k_attn3<<<(NN * 64 + 255) / 256, 256, 0, stream>>>(xlr, attv + l * 512, bgv + l * 512,
                                                       rowptr, col, NN);
  };

  // Layer 1
  gemm(xc, 1024, comb0, cb + 0 * 1024, X0, NN, 1024, 1024, 0);
  attn(X0, 0);
  // Layer 2
  gemm(X0 + 512, 1024, combL[1], cb + 1 * 1024, X1, NN, 1024, 512, 0);
  attn(X1, 1);
  // Layer 3
  gemm(X1 + 512, 1024, combL[2], cb + 2 * 1024, X0, NN, 1024, 512, 0);
  attn(X0, 2);
  // Layer 4
  gemm(X0 + 512, 1024, combL[3], cb + 3 * 1024, X1, NN, 1024, 512, 0);
  attn(X1, 3);

  // MLP head
  gemm(X1 + 512, 1024, lw1T, lb1v, mlp1, NN, 512, 512, 1);
  gemm(mlp1, 512, lw2T, lb2v, mlp2, NN, 256, 512, 1);
  k_head<<<(NN * 64 + 255) / 256, 256, 0, stream>>>(mlp2, lw3v, lb3v, (float*)d_out, NN);
}